// Round 6
// baseline (139.190 us; speedup 1.0000x reference)
//
#include <hip/hip_runtime.h>

typedef short short8 __attribute__((ext_vector_type(8)));
typedef __bf16 bf16x8 __attribute__((ext_vector_type(8)));
typedef float floatx4 __attribute__((ext_vector_type(4)));

__device__ __forceinline__ float make_pow2(int e) {
  return __builtin_bit_cast(float, (unsigned)((e + 127) << 23));
}

typedef __attribute__((address_space(3))) void lds_void;
typedef const __attribute__((address_space(1))) void glob_void;
__device__ __forceinline__ void gload_lds16(const void* g, void* l) {
  __builtin_amdgcn_global_load_lds((glob_void*)g, (lds_void*)l, 16, 0, 0);
}

// Raw barrier: drains LDS ops only (NO vmcnt drain — global loads stay in flight).
__device__ __forceinline__ void barrier_lgkm() {
  asm volatile("s_waitcnt lgkmcnt(0)" ::: "memory");
  __builtin_amdgcn_sched_barrier(0);
  __builtin_amdgcn_s_barrier();
  asm volatile("" ::: "memory");
  __builtin_amdgcn_sched_barrier(0);
}

template <int N> __device__ __forceinline__ void wait_vmcnt() {
  asm volatile("s_waitcnt vmcnt(%0)" :: "n"(N) : "memory");
  __builtin_amdgcn_sched_barrier(0);
}

// ---------------- Phase 1: quantize weights -> bf16 in workspace ----------------
__global__ void quant_w_kernel(const float* __restrict__ w, unsigned short* __restrict__ qw) {
  int b = blockIdx.x;                 // 0..4607
  int row = b / 18, kb = b - row * 18;
  int t = threadIdx.x;                // 0..63
  int idx = row * 1152 + kb * 64 + t;
  float v = w[idx];
  float a = fabsf(v);
  #pragma unroll
  for (int off = 32; off; off >>= 1) a = fmaxf(a, __shfl_xor(a, off));
  float q = 0.f;
  if (a > 0.f) {
    int e = (int)((__builtin_bit_cast(unsigned, a) >> 23) & 0xffu) - 127;
    if (e < -126) e = -126;
    float inv = make_pow2(6 - e);
    float s   = make_pow2(e - 6);
    float r = rintf(v * inv);
    r = fminf(fmaxf(r, -128.f), 127.f);
    q = r * s;
  }
  qw[idx] = (unsigned short)(__builtin_bit_cast(unsigned, q) >> 16);
}

// ---------------- Phase 2: fused im2col + BFP-quantize + GEMM ----------------
// M=100352, N=256, K=1152. BM=64, BN=256, BK=64. 512 thr = 8 waves; wave owns a
// 32-col N-slab (acc[4][2]). Depth-4 pipeline with raw barriers + counted vmcnt:
// phase kb = MFMA(kb) + quantize(kb+1) + stageB(kb+1) + gather(kb+3) + lmax(kb+2).
// Bs is per-wave private (wave stages exactly the rows its MFMAs read) -> stage
// needs only a per-wave vmcnt, never a barrier. Barriers order As/pmax only.
__global__ __launch_bounds__(512, 4) void conv_bfp_kernel(
    const float* __restrict__ in, const unsigned short* __restrict__ qw,
    const float* __restrict__ bias, float* __restrict__ out) {
  __shared__ unsigned short As[64 * 64];       // 8 KB single-buffer (frags preloaded)
  __shared__ unsigned short Bs[2][256 * 64];   // 64 KB double-buffer
  __shared__ float pmax[2][8][64];             // [buf][wave][row], conflict-free

  const int bid = blockIdx.x;
  const int mt = (bid & 7) * 196 + (bid >> 3);   // XCD-chunked swizzle (1568 = 8*196)
  const int t = threadIdx.x;
  const int lane = t & 63;
  const int wave = __builtin_amdgcn_readfirstlane(t >> 6);

  // ---- pixel geometry (A row = lane) ----
  const unsigned m = mt * 64u + lane;
  const unsigned nimg = m / 3136u;
  const unsigned py = m - nimg * 3136u;
  const int y = (int)(py / 56u);
  const int x = (int)(py - (unsigned)y * 56u);
  const int vbase = (int)((nimg * 401408u + (unsigned)y * 56u + (unsigned)x) * 4u);
  int vm = 0;
  #pragma unroll
  for (int i = 0; i < 3; ++i)
    #pragma unroll
    for (int j = 0; j < 3; ++j)
      if ((unsigned)(y + i - 1) < 56u && (unsigned)(x + j - 1) < 56u)
        vm |= 1 << (i * 3 + j);

  // ---- B staging (wave w stages rows w*32..+31; pre-swizzled source chunks) ----
  const int l3 = lane >> 3, l7 = lane & 7;
  const char* bsrc = (const char*)qw + (size_t)((wave * 32 + l3) * 2304) + ((l7 ^ l3) * 16);

  const int lr = lane & 15;
  const int lk = (lane >> 4) << 4;
  const int swz = (lr & 7) << 4;

  floatx4 acc[4][2] = {};

  auto gather = [&](float (&av)[8], int kb) {
    const int k0 = __builtin_amdgcn_readfirstlane(kb * 64 + wave * 8);
    #pragma unroll
    for (int u = 0; u < 8; ++u) {
      int k = k0 + u;                          // scalar
      int c = (int)((unsigned)k / 9u);
      int ij = k - c * 9;
      int soff = c * 3136 + (ij / 3) * 56 + (ij % 3) - 57;
      const char* pk = (const char*)in + (ptrdiff_t)soff * 4;
      float v = 0.f;
      if ((vm >> ij) & 1)
        v = *(const float*)(pk + vbase);       // global_load_dword v, vbase, s[pk]
      av[u] = v;
    }
  };

  auto stage = [&](int kb) {                   // stage k-block kb -> Bs[kb&1] (4 loads)
    char* bdst = (char*)Bs[kb & 1] + wave * 4096;
    #pragma unroll
    for (int c8 = 0; c8 < 4; ++c8)
      gload_lds16(bsrc + (size_t)c8 * 18432 + kb * 128, bdst + c8 * 1024);
  };

  auto lmax_store = [&](float (&av)[8], int kb) {
    float lm = 0.f;
    #pragma unroll
    for (int u = 0; u < 8; ++u) lm = fmaxf(lm, fabsf(av[u]));
    pmax[kb & 1][wave][lane] = lm;
  };

  auto quantWrite = [&](float (&av)[8], int kb) {
    const float* pb = &pmax[kb & 1][0][lane];
    float ma = 0.f;
    #pragma unroll
    for (int j = 0; j < 8; ++j) ma = fmaxf(ma, pb[j * 64]);
    short8 aq;
    if (ma > 0.f) {
      int e = (int)((__builtin_bit_cast(unsigned, ma) >> 23) & 0xffu) - 127;
      if (e < -126) e = -126;
      float inv = make_pow2(6 - e);
      float s   = make_pow2(e - 6);
      #pragma unroll
      for (int u = 0; u < 8; ++u) {
        float r = rintf(av[u] * inv);
        r = fminf(fmaxf(r, -128.f), 127.f);
        float q = r * s;
        aq[u] = (short)(unsigned short)(__builtin_bit_cast(unsigned, q) >> 16);
      }
    } else {
      aq = (short8)0;
    }
    char* arow = (char*)As + lane * 128;
    *(short8*)(arow + ((wave * 16) ^ ((lane & 7) << 4))) = aq;
  };

  auto preloadA = [&](bf16x8 (&afr)[2][4]) {
    #pragma unroll
    for (int ks = 0; ks < 2; ++ks)
      #pragma unroll
      for (int f = 0; f < 4; ++f)
        afr[ks][f] = __builtin_bit_cast(bf16x8,
            *(const short8*)((const char*)As + (f * 16 + lr) * 128 + ((ks * 64 + lk) ^ swz)));
  };

  auto mfmaBlk = [&](bf16x8 (&afr)[2][4], int kb) {
    const char* bbase = (const char*)Bs[kb & 1];
    __builtin_amdgcn_s_setprio(1);
    #pragma unroll
    for (int ks = 0; ks < 2; ++ks) {
      const int kbyte = (ks * 64 + lk) ^ swz;
      bf16x8 bfr[2];
      #pragma unroll
      for (int f = 0; f < 2; ++f)
        bfr[f] = __builtin_bit_cast(bf16x8,
            *(const short8*)(bbase + (wave * 32 + f * 16 + lr) * 128 + kbyte));
      #pragma unroll
      for (int fm = 0; fm < 4; ++fm)
        #pragma unroll
        for (int fn = 0; fn < 2; ++fn)
          acc[fm][fn] = __builtin_amdgcn_mfma_f32_16x16x32_bf16(bfr[fn], afr[ks][fm], acc[fm][fn], 0, 0, 0);
    }
    __builtin_amdgcn_s_setprio(0);
  };

  float avA[8], avB[8], avC[8];

  // ---- prologue (no vmcnt drains; barriers order pmax/As only) ----
  stage(0);
  gather(avA, 0);
  gather(avB, 1);
  lmax_store(avA, 0);              // auto-waits av0 regs only
  barrier_lgkm();                  // pmax(0) visible
  quantWrite(avA, 0);              // As <- kb 0
  gather(avC, 2);
  lmax_store(avB, 1);
  barrier_lgkm();                  // As(0), pmax(1) visible

  // Steady phase kb (kb<=14): q=av(kb+1), l=av(kb+2), g=gather av(kb+3).
  // vmcnt(20): loads newer than stage(kb) = gather(kb+2)[8]+stage(kb+1)[4]+gather(kb+3)[8].
  auto phase = [&](int kb, float (&q)[8], float (&l)[8], float (&g)[8]) {
    bf16x8 afr[2][4];
    preloadA(afr);                 // As holds kb
    barrier_lgkm();                // all waves' A reads in regs -> As reusable
    quantWrite(q, kb + 1);         // As <- kb+1 (pmax[(kb+1)&1])
    stage(kb + 1);                 // Bs[(kb+1)&1], per-wave private
    gather(g, kb + 3);
    wait_vmcnt<20>();              // stage(kb) landed in Bs[kb&1]
    mfmaBlk(afr, kb);
    lmax_store(l, kb + 2);         // auto-waits gather(kb+2) (full phase of cover)
    barrier_lgkm();                // As(kb+1)+pmax(kb+2) visible
  };

  #pragma unroll 1
  for (int kb = 0; kb < 15; kb += 3) {
    phase(kb,     avB, avC, avA);
    phase(kb + 1, avC, avA, avB);
    phase(kb + 2, avA, avB, avC);
  }

  // ---- tail: kb = 15, 16, 17 (no more gathers) ----
  {
    bf16x8 afr[2][4];
    preloadA(afr);                 // As holds 15
    barrier_lgkm();
    quantWrite(avB, 16);
    stage(16);
    wait_vmcnt<12>();              // newer than stage(15): gather(17)[8]+stage(16)[4]
    mfmaBlk(afr, 15);
    lmax_store(avC, 17);
    barrier_lgkm();
  }
  {
    bf16x8 afr[2][4];
    preloadA(afr);                 // As holds 16
    barrier_lgkm();
    quantWrite(avC, 17);
    stage(17);
    wait_vmcnt<4>();               // newer than stage(16): stage(17)[4]
    mfmaBlk(afr, 16);
    barrier_lgkm();
  }
  {
    bf16x8 afr[2][4];
    preloadA(afr);                 // As holds 17
    wait_vmcnt<0>();               // stage(17) landed
    mfmaBlk(afr, 17);
  }

  // ---- epilogue: D[co][pix]; 3136 = 49*64 so the 64-row tile is one image ----
  const unsigned ni = (mt * 64u) / 3136u;
  const unsigned pp0 = mt * 64u - ni * 3136u;
  float* obase = out + (size_t)ni * 802816u + pp0;
  const int cg = (lane >> 4) << 2;
  #pragma unroll
  for (int fn = 0; fn < 2; ++fn) {
    floatx4 bv = *(const floatx4*)&bias[wave * 32 + fn * 16 + cg];
    #pragma unroll
    for (int r = 0; r < 4; ++r) {
      int co = wave * 32 + fn * 16 + cg + r;
      float* orow = obase + (size_t)co * 3136u;
      #pragma unroll
      for (int fm = 0; fm < 4; ++fm)
        orow[fm * 16 + lr] = acc[fm][fn][r] + bv[r];
    }
  }
}

extern "C" void kernel_launch(void* const* d_in, const int* in_sizes, int n_in,
                              void* d_out, int out_size, void* d_ws, size_t ws_size,
                              hipStream_t stream) {
  const float* in   = (const float*)d_in[0];
  const float* w    = (const float*)d_in[1];
  const float* bias = (const float*)d_in[2];
  float* out = (float*)d_out;
  unsigned short* qw = (unsigned short*)d_ws;   // 256*1152*2 = 589824 B

  quant_w_kernel<<<4608, 64, 0, stream>>>(w, qw);
  conv_bfp_kernel<<<1568, 512, 0, stream>>>(in, qw, bias, out);
}

// Round 7
// 130.565 us; speedup vs baseline: 1.0661x; 1.0661x over previous
//
#include <hip/hip_runtime.h>

typedef short short8 __attribute__((ext_vector_type(8)));
typedef __bf16 bf16x8 __attribute__((ext_vector_type(8)));
typedef float floatx4 __attribute__((ext_vector_type(4)));

__device__ __forceinline__ float make_pow2(int e) {
  return __builtin_bit_cast(float, (unsigned)((e + 127) << 23));
}

// Raw barrier: drains LDS ops only (global loads stay in flight; they are all
// to-register, so ordinary register dependencies handle their waits).
__device__ __forceinline__ void barrier_lgkm() {
  asm volatile("s_waitcnt lgkmcnt(0)" ::: "memory");
  __builtin_amdgcn_sched_barrier(0);
  __builtin_amdgcn_s_barrier();
  asm volatile("" ::: "memory");
  __builtin_amdgcn_sched_barrier(0);
}

// ---------------- Phase 1: quantize weights -> bf16 FRAGMENT-ORDER blob ----------------
// Blob layout: [ct(16)][kb(18)][ks(2)][lane(64)][j(8)] bf16, where the value at
// (ct,kb,ks,lane,j) is qW[co = ct*16 + (lane&15)][k = kb*64 + ks*32 + (lane>>4)*8 + j].
// This is exactly the mfma A-slot fragment layout, so the GEMM does
// global_load_dwordx4 straight into MFMA operands. One wave per (ct,kb).
__global__ void quant_w_kernel(const float* __restrict__ w, unsigned short* __restrict__ qw) {
  int b = blockIdx.x;                 // 0..287
  int ct = b / 18, kb = b - ct * 18;
  int L = threadIdx.x;                // 0..63
  int co = ct * 16 + (L & 15);
  int kq = L >> 4;                    // 0..3
  const float* wr = w + co * 1152 + kb * 64 + kq * 8;
  float v[16];
  float a = 0.f;
  #pragma unroll
  for (int ks = 0; ks < 2; ++ks)
    #pragma unroll
    for (int j = 0; j < 8; ++j) {
      float t = wr[ks * 32 + j];
      v[ks * 8 + j] = t;
      a = fmaxf(a, fabsf(t));
    }
  // per-(co, k-block) max: union over the 4 kq-lanes sharing co  (lanes L, L^16, L^32, L^48)
  a = fmaxf(a, __shfl_xor(a, 16));
  a = fmaxf(a, __shfl_xor(a, 32));
  short8 q0 = (short8)0, q1 = (short8)0;
  if (a > 0.f) {
    int e = (int)((__builtin_bit_cast(unsigned, a) >> 23) & 0xffu) - 127;
    if (e < -126) e = -126;
    float inv = make_pow2(6 - e);
    float s   = make_pow2(e - 6);
    #pragma unroll
    for (int u = 0; u < 16; ++u) {
      float r = rintf(v[u] * inv);
      r = fminf(fmaxf(r, -128.f), 127.f);
      float qq = r * s;
      unsigned short hb = (unsigned short)(__builtin_bit_cast(unsigned, qq) >> 16);
      if (u < 8) q0[u] = (short)hb; else q1[u - 8] = (short)hb;
    }
  }
  unsigned short* dst = qw + (size_t)(ct * 18 + kb) * 1024;   // 2 sections of 512 ushort
  *(short8*)(dst + L * 8) = q0;          // ks = 0
  *(short8*)(dst + 512 + L * 8) = q1;    // ks = 1
}

// ---------------- Phase 2: fused im2col + BFP-quantize + GEMM ----------------
// M=100352, N=256, K=1152. BM=64, BN=256, BK=64. 512 thr = 8 waves; wave owns a
// 32-col N-slab (acc[4][2]) and an 8-wide k-slice of the A gather/quantize.
// B comes straight from the fragment blob (global->VGPR, L2-resident, double-
// buffered one phase ahead). LDS holds only As (dbuf) + pmax (dbuf): one
// lgkm-barrier per phase.
__global__ __launch_bounds__(512, 4) void conv_bfp_kernel(
    const float* __restrict__ in, const unsigned short* __restrict__ qw,
    const float* __restrict__ bias, float* __restrict__ out) {
  __shared__ unsigned short As[2][64 * 64];    // 16 KB double-buffer
  __shared__ float pmax[2][8][64];             // 4 KB  [buf][wave][row]

  const int bid = blockIdx.x;
  const int mt = (bid & 7) * 196 + (bid >> 3);   // XCD-chunked swizzle (1568 = 8*196)
  const int t = threadIdx.x;
  const int lane = t & 63;
  const int wave = __builtin_amdgcn_readfirstlane(t >> 6);

  // ---- pixel geometry (A row = lane) ----
  const unsigned m = mt * 64u + lane;
  const unsigned nimg = m / 3136u;
  const unsigned py = m - nimg * 3136u;
  const int y = (int)(py / 56u);
  const int x = (int)(py - (unsigned)y * 56u);
  const int vbase = (int)((nimg * 401408u + (unsigned)y * 56u + (unsigned)x) * 4u);
  int vm = 0;
  #pragma unroll
  for (int i = 0; i < 3; ++i)
    #pragma unroll
    for (int j = 0; j < 3; ++j)
      if ((unsigned)(y + i - 1) < 56u && (unsigned)(x + j - 1) < 56u)
        vm |= 1 << (i * 3 + j);

  const int lr = lane & 15;
  const int lk = (lane >> 4) << 4;
  const int swz = (lr & 7) << 4;

  floatx4 acc[4][2] = {};

  auto gather = [&](float (&av)[8], int kb) {
    const int k0 = __builtin_amdgcn_readfirstlane(kb * 64 + wave * 8);
    #pragma unroll
    for (int u = 0; u < 8; ++u) {
      int k = k0 + u;                          // scalar
      int c = (int)((unsigned)k / 9u);
      int ij = k - c * 9;
      int soff = c * 3136 + (ij / 3) * 56 + (ij % 3) - 57;
      const char* pk = (const char*)in + (ptrdiff_t)soff * 4;
      float v = 0.f;
      if ((vm >> ij) & 1)
        v = *(const float*)(pk + vbase);       // global_load_dword v, vbase, s[pk]
      av[u] = v;
    }
  };

  auto loadB = [&](bf16x8 (&bq)[2][2], int kb) {   // [ks][fn], 4x global dwordx4
    #pragma unroll
    for (int ks = 0; ks < 2; ++ks)
      #pragma unroll
      for (int fn = 0; fn < 2; ++fn) {
        int ct = wave * 2 + fn;
        bq[ks][fn] = __builtin_bit_cast(bf16x8, *(const short8*)(
            (const char*)qw + ((size_t)((ct * 18 + kb) * 2 + ks) * 64 + lane) * 16));
      }
  };

  auto lmax_store = [&](float (&av)[8], int kb) {
    float lm = 0.f;
    #pragma unroll
    for (int u = 0; u < 8; ++u) lm = fmaxf(lm, fabsf(av[u]));
    pmax[kb & 1][wave][lane] = lm;
  };

  auto quantWrite = [&](float (&av)[8], int kb) {  // -> As[kb&1], reads pmax[kb&1]
    const float* pb = &pmax[kb & 1][0][lane];
    float ma = 0.f;
    #pragma unroll
    for (int j = 0; j < 8; ++j) ma = fmaxf(ma, pb[j * 64]);
    short8 aq;
    if (ma > 0.f) {
      int e = (int)((__builtin_bit_cast(unsigned, ma) >> 23) & 0xffu) - 127;
      if (e < -126) e = -126;
      float inv = make_pow2(6 - e);
      float s   = make_pow2(e - 6);
      #pragma unroll
      for (int u = 0; u < 8; ++u) {
        float r = rintf(av[u] * inv);
        r = fminf(fmaxf(r, -128.f), 127.f);
        float q = r * s;
        aq[u] = (short)(unsigned short)(__builtin_bit_cast(unsigned, q) >> 16);
      }
    } else {
      aq = (short8)0;
    }
    char* arow = (char*)As[kb & 1] + lane * 128;
    *(short8*)(arow + ((wave * 16) ^ ((lane & 7) << 4))) = aq;
  };

  auto mfmaBlk = [&](bf16x8 (&bq)[2][2], int kb) {  // reads As[kb&1]
    const char* abase = (const char*)As[kb & 1];
    __builtin_amdgcn_s_setprio(1);
    #pragma unroll
    for (int ks = 0; ks < 2; ++ks) {
      const int kbyte = (ks * 64 + lk) ^ swz;
      #pragma unroll
      for (int fm = 0; fm < 4; ++fm) {
        bf16x8 af = __builtin_bit_cast(bf16x8,
            *(const short8*)(abase + (fm * 16 + lr) * 128 + kbyte));
        #pragma unroll
        for (int fn = 0; fn < 2; ++fn)
          acc[fm][fn] = __builtin_amdgcn_mfma_f32_16x16x32_bf16(bq[ks][fn], af, acc[fm][fn], 0, 0, 0);
      }
    }
    __builtin_amdgcn_s_setprio(0);
  };

  float av0[8], av1[8];
  bf16x8 bqA[2][2], bqB[2][2];

  // ---- prologue ----
  gather(av0, 0);
  loadB(bqA, 0);
  gather(av1, 1);
  lmax_store(av0, 0);              // pmax[0]
  lmax_store(av1, 1);              // pmax[1]
  barrier_lgkm();                  // pmax 0,1 visible
  quantWrite(av0, 0);              // As[0] <- kb 0
  // (phase 0's opening barrier makes As[0] visible)

  // Phase kb: MFMA(kb) from As[kb&1]+bq_cur; quant av(kb+1)->As[(kb+1)&1];
  // gather av(kb+2); loadB(kb+1)->bq_nxt; lmax(kb+2)->pmax[(kb+2)&1].
  auto phase = [&](int kb, float (&avq)[8], float (&avg)[8],
                   bf16x8 (&bqc)[2][2], bf16x8 (&bqn)[2][2]) {
    barrier_lgkm();                // As[(kb)&1]+pmax writes from prev phase visible
    if (kb < 17) quantWrite(avq, kb + 1);
    if (kb < 16) gather(avg, kb + 2);
    if (kb < 17) loadB(bqn, kb + 1);
    mfmaBlk(bqc, kb);
    if (kb < 16) lmax_store(avg, kb + 2);
  };

  #pragma unroll 1
  for (int kb = 0; kb < 18; kb += 2) {
    phase(kb,     av1, av0, bqA, bqB);
    phase(kb + 1, av0, av1, bqB, bqA);
  }

  // ---- epilogue: D[co][pix]; 3136 = 49*64 so the 64-row tile is one image ----
  const unsigned ni = (mt * 64u) / 3136u;
  const unsigned pp0 = mt * 64u - ni * 3136u;
  float* obase = out + (size_t)ni * 802816u + pp0;
  const int cg = (lane >> 4) << 2;
  #pragma unroll
  for (int fn = 0; fn < 2; ++fn) {
    floatx4 bv = *(const floatx4*)&bias[wave * 32 + fn * 16 + cg];
    #pragma unroll
    for (int r = 0; r < 4; ++r) {
      int co = wave * 32 + fn * 16 + cg + r;
      float* orow = obase + (size_t)co * 3136u;
      #pragma unroll
      for (int fm = 0; fm < 4; ++fm)
        orow[fm * 16 + lr] = acc[fm][fn][r] + bv[r];
    }
  }
}

extern "C" void kernel_launch(void* const* d_in, const int* in_sizes, int n_in,
                              void* d_out, int out_size, void* d_ws, size_t ws_size,
                              hipStream_t stream) {
  const float* in   = (const float*)d_in[0];
  const float* w    = (const float*)d_in[1];
  const float* bias = (const float*)d_in[2];
  float* out = (float*)d_out;
  unsigned short* qw = (unsigned short*)d_ws;   // 16*18*1024 ushort = 589824 B

  quant_w_kernel<<<288, 64, 0, stream>>>(w, qw);
  conv_bfp_kernel<<<1568, 512, 0, stream>>>(in, qw, bias, out);
}

// Round 8
// 125.945 us; speedup vs baseline: 1.1052x; 1.0367x over previous
//
#include <hip/hip_runtime.h>

typedef short short8 __attribute__((ext_vector_type(8)));
typedef __bf16 bf16x8 __attribute__((ext_vector_type(8)));
typedef float floatx4 __attribute__((ext_vector_type(4)));

__device__ __forceinline__ float make_pow2(int e) {
  return __builtin_bit_cast(float, (unsigned)((e + 127) << 23));
}

// Raw barrier: drains LDS ops only (global loads stay in flight; they are all
// to-register, so ordinary register dependencies handle their waits).
__device__ __forceinline__ void barrier_lgkm() {
  asm volatile("s_waitcnt lgkmcnt(0)" ::: "memory");
  __builtin_amdgcn_sched_barrier(0);
  __builtin_amdgcn_s_barrier();
  asm volatile("" ::: "memory");
  __builtin_amdgcn_sched_barrier(0);
}

// ---------------- Phase 1: quantize weights -> bf16 FRAGMENT-ORDER blob ----------------
// Blob layout: [ct(16)][kb(18)][ks(2)][lane(64)][j(8)] bf16 = mfma src0 frag order.
__global__ void quant_w_kernel(const float* __restrict__ w, unsigned short* __restrict__ qw) {
  int b = blockIdx.x;                 // 0..287
  int ct = b / 18, kb = b - ct * 18;
  int L = threadIdx.x;                // 0..63
  int co = ct * 16 + (L & 15);
  int kq = L >> 4;                    // 0..3
  const float* wr = w + co * 1152 + kb * 64 + kq * 8;
  float v[16];
  float a = 0.f;
  #pragma unroll
  for (int ks = 0; ks < 2; ++ks)
    #pragma unroll
    for (int j = 0; j < 8; ++j) {
      float t = wr[ks * 32 + j];
      v[ks * 8 + j] = t;
      a = fmaxf(a, fabsf(t));
    }
  a = fmaxf(a, __shfl_xor(a, 16));
  a = fmaxf(a, __shfl_xor(a, 32));
  short8 q0 = (short8)0, q1 = (short8)0;
  if (a > 0.f) {
    int e = (int)((__builtin_bit_cast(unsigned, a) >> 23) & 0xffu) - 127;
    if (e < -126) e = -126;
    float inv = make_pow2(6 - e);
    float s   = make_pow2(e - 6);
    #pragma unroll
    for (int u = 0; u < 16; ++u) {
      float r = rintf(v[u] * inv);
      r = fminf(fmaxf(r, -128.f), 127.f);
      float qq = r * s;
      unsigned short hb = (unsigned short)(__builtin_bit_cast(unsigned, qq) >> 16);
      if (u < 8) q0[u] = (short)hb; else q1[u - 8] = (short)hb;
    }
  }
  unsigned short* dst = qw + (size_t)(ct * 18 + kb) * 1024;
  *(short8*)(dst + L * 8) = q0;          // ks = 0
  *(short8*)(dst + 512 + L * 8) = q1;    // ks = 1
}

// ---------------- Phase 2: fused im2col + BFP-quantize + GEMM ----------------
// M=100352, N=256, K=1152. BM=64, BN=256. 512 thr = 8 waves; wave owns a 32-col
// N-slab (acc[4][2]). 2-kb SUPERPHASE, one lgkm-barrier per 128 K: 4-slot
// rotation of As/pmax/av. Superphase kb: mfma(kb)+mfma(kb+1), quant(kb+2,3),
// gather(kb+4,5), lmax(kb+4,5). All slots disjoint within a superphase.
__global__ __launch_bounds__(512, 4) void conv_bfp_kernel(
    const float* __restrict__ in, const unsigned short* __restrict__ qw,
    const float* __restrict__ bias, float* __restrict__ out) {
  __shared__ unsigned short As[4][64 * 64];    // 32 KB, 4-slot rotation
  __shared__ float pmax[4][8][64];             // 8 KB  [slot][wave][row]

  const int bid = blockIdx.x;
  const int mt = (bid & 7) * 196 + (bid >> 3);   // XCD-chunked swizzle (1568 = 8*196)
  const int t = threadIdx.x;
  const int lane = t & 63;
  const int wave = __builtin_amdgcn_readfirstlane(t >> 6);

  // ---- pixel geometry (A row = lane) ----
  const unsigned m = mt * 64u + lane;
  const unsigned nimg = m / 3136u;
  const unsigned py = m - nimg * 3136u;
  const int y = (int)(py / 56u);
  const int x = (int)(py - (unsigned)y * 56u);
  const int vbase = (int)((nimg * 401408u + (unsigned)y * 56u + (unsigned)x) * 4u);
  int vm = 0;
  #pragma unroll
  for (int i = 0; i < 3; ++i)
    #pragma unroll
    for (int j = 0; j < 3; ++j)
      if ((unsigned)(y + i - 1) < 56u && (unsigned)(x + j - 1) < 56u)
        vm |= 1 << (i * 3 + j);

  const int lr = lane & 15;
  const int lk = (lane >> 4) << 4;
  const int swz = (lr & 7) << 4;

  floatx4 acc[4][2] = {};

  auto gather = [&](float (&av)[8], int kb) {
    const int k0 = __builtin_amdgcn_readfirstlane(kb * 64 + wave * 8);
    #pragma unroll
    for (int u = 0; u < 8; ++u) {
      int k = k0 + u;                          // scalar
      int c = (int)((unsigned)k / 9u);
      int ij = k - c * 9;
      int soff = c * 3136 + (ij / 3) * 56 + (ij % 3) - 57;
      const char* pk = (const char*)in + (ptrdiff_t)soff * 4;
      float v = 0.f;
      if ((vm >> ij) & 1)
        v = *(const float*)(pk + vbase);       // global_load_dword v, vbase, s[pk]
      av[u] = v;
    }
  };

  auto loadB = [&](bf16x8 (&bq)[2][2], int kb) {   // [ks][fn], 4x global dwordx4
    #pragma unroll
    for (int ks = 0; ks < 2; ++ks)
      #pragma unroll
      for (int fn = 0; fn < 2; ++fn) {
        int ct = wave * 2 + fn;
        bq[ks][fn] = __builtin_bit_cast(bf16x8, *(const short8*)(
            (const char*)qw + ((size_t)((ct * 18 + kb) * 2 + ks) * 64 + lane) * 16));
      }
  };

  auto lmax_store = [&](float (&av)[8], int kb) {
    float lm = 0.f;
    #pragma unroll
    for (int u = 0; u < 8; ++u) lm = fmaxf(lm, fabsf(av[u]));
    pmax[kb & 3][wave][lane] = lm;
  };

  auto quantWrite = [&](float (&av)[8], int kb) {  // -> As[kb&3], reads pmax[kb&3]
    const float* pb = &pmax[kb & 3][0][lane];
    float ma = 0.f;
    #pragma unroll
    for (int j = 0; j < 8; ++j) ma = fmaxf(ma, pb[j * 64]);
    short8 aq;
    if (ma > 0.f) {
      int e = (int)((__builtin_bit_cast(unsigned, ma) >> 23) & 0xffu) - 127;
      if (e < -126) e = -126;
      float inv = make_pow2(6 - e);
      float s   = make_pow2(e - 6);
      #pragma unroll
      for (int u = 0; u < 8; ++u) {
        float r = rintf(av[u] * inv);
        r = fminf(fmaxf(r, -128.f), 127.f);
        float q = r * s;
        aq[u] = (short)(unsigned short)(__builtin_bit_cast(unsigned, q) >> 16);
      }
    } else {
      aq = (short8)0;
    }
    char* arow = (char*)As[kb & 3] + lane * 128;
    *(short8*)(arow + ((wave * 16) ^ ((lane & 7) << 4))) = aq;
  };

  auto mfmaBlk = [&](bf16x8 (&bq)[2][2], int kb) {  // reads As[kb&3]
    const char* abase = (const char*)As[kb & 3];
    __builtin_amdgcn_s_setprio(1);
    #pragma unroll
    for (int ks = 0; ks < 2; ++ks) {
      const int kbyte = (ks * 64 + lk) ^ swz;
      #pragma unroll
      for (int fm = 0; fm < 4; ++fm) {
        bf16x8 af = __builtin_bit_cast(bf16x8,
            *(const short8*)(abase + (fm * 16 + lr) * 128 + kbyte));
        #pragma unroll
        for (int fn = 0; fn < 2; ++fn)
          acc[fm][fn] = __builtin_amdgcn_mfma_f32_16x16x32_bf16(bq[ks][fn], af, acc[fm][fn], 0, 0, 0);
      }
    }
    __builtin_amdgcn_s_setprio(0);
  };

  // Superphase: one barrier per 2 kb. q0/q1 hold gathered kb+2/kb+3;
  // g0/g1 receive kb+4/kb+5.
  auto superp = [&](int kb, float (&q0)[8], float (&q1)[8],
                    float (&g0)[8], float (&g1)[8]) {
    barrier_lgkm();                // As[kb&3],[kb+1&3] + pmax[(kb+2)&3],[(kb+3)&3] visible
    bf16x8 bq[2][2], bq2[2][2];
    loadB(bq, kb);
    if (kb + 2 < 18) { quantWrite(q0, kb + 2); quantWrite(q1, kb + 3); }
    if (kb + 4 < 18) { gather(g0, kb + 4); gather(g1, kb + 5); }
    loadB(bq2, kb + 1);            // covered by mfma(kb)
    mfmaBlk(bq, kb);
    if (kb + 4 < 18) { lmax_store(g0, kb + 4); lmax_store(g1, kb + 5); }
    mfmaBlk(bq2, kb + 1);
  };

  float gA[8], gB[8], gC[8], gD[8];

  // ---- prologue: fill pmax 0..3 and As 0,1 ----
  gather(gA, 0); gather(gB, 1); gather(gC, 2); gather(gD, 3);
  lmax_store(gA, 0); lmax_store(gB, 1); lmax_store(gC, 2); lmax_store(gD, 3);
  barrier_lgkm();                  // pmax 0..3 visible
  quantWrite(gA, 0); quantWrite(gB, 1);   // As0, As1  (gA,gB free)

  #pragma unroll 1
  for (int kb = 0; kb < 16; kb += 4) {
    superp(kb,     gC, gD, gA, gB);   // quant kb+2,kb+3; gather kb+4,kb+5
    superp(kb + 2, gA, gB, gC, gD);
  }
  superp(16, gC, gD, gA, gB);         // mfma 16,17 only (guards skip the rest)

  // ---- epilogue: D[co][pix]; 3136 = 49*64 so the 64-row tile is one image ----
  const unsigned ni = (mt * 64u) / 3136u;
  const unsigned pp0 = mt * 64u - ni * 3136u;
  float* obase = out + (size_t)ni * 802816u + pp0;
  const int cg = (lane >> 4) << 2;
  #pragma unroll
  for (int fn = 0; fn < 2; ++fn) {
    floatx4 bv = *(const floatx4*)&bias[wave * 32 + fn * 16 + cg];
    #pragma unroll
    for (int r = 0; r < 4; ++r) {
      int co = wave * 32 + fn * 16 + cg + r;
      float* orow = obase + (size_t)co * 3136u;
      #pragma unroll
      for (int fm = 0; fm < 4; ++fm)
        orow[fm * 16 + lr] = acc[fm][fn][r] + bv[r];
    }
  }
}

extern "C" void kernel_launch(void* const* d_in, const int* in_sizes, int n_in,
                              void* d_out, int out_size, void* d_ws, size_t ws_size,
                              hipStream_t stream) {
  const float* in   = (const float*)d_in[0];
  const float* w    = (const float*)d_in[1];
  const float* bias = (const float*)d_in[2];
  float* out = (float*)d_out;
  unsigned short* qw = (unsigned short*)d_ws;   // 16*18*1024 ushort = 589824 B

  quant_w_kernel<<<288, 64, 0, stream>>>(w, qw);
  conv_bfp_kernel<<<1568, 512, 0, stream>>>(in, qw, bias, out);
}